// Round 1
// baseline (2323.690 us; speedup 1.0000x reference)
//
#include <hip/hip_runtime.h>

#define BB 16
#define TT 8
#define CC 1024
#define SPAST 8192
#define SEQ (SPAST + TT)      // 8200
#define QSCALE 0.03125f       // 1024^-0.5
#define VCHUNK 512
#define NCHUNK 17             // ceil(8200/512)

// ---------------- K1: qkv = x @ w_qkv + b_qkv ----------------
// q*scale -> ws_q ; k_new/v_new -> tails of k_out/v_out
__global__ __launch_bounds__(256) void k_qkv(const float* __restrict__ x,
                                             const float* __restrict__ w,
                                             const float* __restrict__ bias,
                                             float* __restrict__ q,
                                             float* __restrict__ k_out,
                                             float* __restrict__ v_out) {
    __shared__ float xs[TT * CC];                 // 32 KB: 8 rows of x for this b
    const int tid = threadIdx.x;
    const int b   = blockIdx.y;                   // 0..15 (rows b*8 .. b*8+7, t=0..7)
    const int col = blockIdx.x * 256 + tid;       // 0..3071

    const float4* src = (const float4*)(x + (size_t)b * TT * CC);
    float4* dst = (float4*)xs;
    for (int i = tid; i < TT * CC / 4; i += 256) dst[i] = src[i];
    __syncthreads();

    float acc[TT];
    const float bv = bias[col];
#pragma unroll
    for (int r = 0; r < TT; ++r) acc[r] = bv;
#pragma unroll 4
    for (int c = 0; c < CC; ++c) {
        const float wv = w[(size_t)c * 3 * CC + col];
#pragma unroll
        for (int r = 0; r < TT; ++r) acc[r] += xs[r * CC + c] * wv;
    }
    if (col < CC) {
#pragma unroll
        for (int r = 0; r < TT; ++r)
            q[(size_t)(b * TT + r) * CC + col] = acc[r] * QSCALE;
    } else if (col < 2 * CC) {
        const int j = col - CC;
#pragma unroll
        for (int r = 0; r < TT; ++r)
            k_out[(size_t)b * SEQ * CC + (size_t)(SPAST + r) * CC + j] = acc[r];
    } else {
        const int j = col - 2 * CC;
#pragma unroll
        for (int r = 0; r < TT; ++r)
            v_out[(size_t)b * SEQ * CC + (size_t)(SPAST + r) * CC + j] = acc[r];
    }
}

// ---------------- K2: copy cache_k -> k_out, fused scores = q . k ----------------
// grid (129, 16): 64 s-rows per block, 4 waves, wave-per-row.
__global__ __launch_bounds__(256) void k_copyk_scores(const float* __restrict__ cache_k,
                                                      const float* __restrict__ q,
                                                      float* __restrict__ k_out,
                                                      float* __restrict__ scores) {
    __shared__ float qs[TT * CC];                 // 32 KB
    const int tid = threadIdx.x;
    const int b   = blockIdx.y;
    const int s0  = blockIdx.x * 64;

    {
        const float4* src = (const float4*)(q + (size_t)b * TT * CC);
        float4* dst = (float4*)qs;
        for (int i = tid; i < TT * CC / 4; i += 256) dst[i] = src[i];
    }
    __syncthreads();

    const int lane = tid & 63;
    const int wv   = tid >> 6;
    const bool tail = (s0 >= SPAST);              // block-uniform (chunks align with 8192)
    const int send = (s0 + 64 < SEQ) ? s0 + 64 : SEQ;

    for (int s = s0 + wv; s < send; s += 4) {
        float acc[TT];
#pragma unroll
        for (int t = 0; t < TT; ++t) acc[t] = 0.f;

        const float4* krow = tail
            ? (const float4*)(k_out   + ((size_t)b * SEQ   + s) * CC)
            : (const float4*)(cache_k + ((size_t)b * SPAST + s) * CC);
        float4* kdst = (float4*)(k_out + ((size_t)b * SEQ + s) * CC);

#pragma unroll
        for (int i = 0; i < 4; ++i) {
            const int c = i * 256 + lane * 4;
            const float4 k4 = krow[c >> 2];
            if (!tail) kdst[c >> 2] = k4;
#pragma unroll
            for (int t = 0; t < TT; ++t) {
                const float4 q4 = *(const float4*)&qs[t * CC + c];
                acc[t] += k4.x * q4.x + k4.y * q4.y + k4.z * q4.z + k4.w * q4.w;
            }
        }
#pragma unroll
        for (int t = 0; t < TT; ++t) {
            float v = acc[t];
            v += __shfl_xor(v, 32);
            v += __shfl_xor(v, 16);
            v += __shfl_xor(v, 8);
            v += __shfl_xor(v, 4);
            v += __shfl_xor(v, 2);
            v += __shfl_xor(v, 1);
            acc[t] = v;
        }
        if (lane == 0) {
#pragma unroll
            for (int t = 0; t < TT; ++t)
                scores[(size_t)(b * TT + t) * SEQ + s] = acc[t];
        }
    }
}

// ---------------- K3: softmax in place over scores rows (128 x 8200) ----------------
__global__ __launch_bounds__(256) void k_softmax(float* __restrict__ scores) {
    float* p = scores + (size_t)blockIdx.x * SEQ;
    const int tid  = threadIdx.x;
    const int lane = tid & 63;
    const int wv   = tid >> 6;
    __shared__ float sred[4];

    float m = -1e30f;
    for (int i = tid; i < SEQ; i += 256) m = fmaxf(m, p[i]);
    m = fmaxf(m, __shfl_xor(m, 32));
    m = fmaxf(m, __shfl_xor(m, 16));
    m = fmaxf(m, __shfl_xor(m, 8));
    m = fmaxf(m, __shfl_xor(m, 4));
    m = fmaxf(m, __shfl_xor(m, 2));
    m = fmaxf(m, __shfl_xor(m, 1));
    if (lane == 0) sred[wv] = m;
    __syncthreads();
    m = fmaxf(fmaxf(sred[0], sred[1]), fmaxf(sred[2], sred[3]));
    __syncthreads();

    float sum = 0.f;
    for (int i = tid; i < SEQ; i += 256) {
        const float e = __expf(p[i] - m);
        p[i] = e;
        sum += e;
    }
    sum += __shfl_xor(sum, 32);
    sum += __shfl_xor(sum, 16);
    sum += __shfl_xor(sum, 8);
    sum += __shfl_xor(sum, 4);
    sum += __shfl_xor(sum, 2);
    sum += __shfl_xor(sum, 1);
    if (lane == 0) sred[wv] = sum;
    __syncthreads();
    const float inv = 1.0f / (sred[0] + sred[1] + sred[2] + sred[3]);
    for (int i = tid; i < SEQ; i += 256) p[i] *= inv;
}

// ---------------- K4: copy cache_v -> v_out, fused ctx partials ----------------
// grid (17, 16): 512 s-rows per block, thread owns 4 columns across all s.
__global__ __launch_bounds__(256) void k_copyv_ctx(const float* __restrict__ cache_v,
                                                   const float* __restrict__ scores,
                                                   float* __restrict__ v_out,
                                                   float* __restrict__ ctx_part) {
    __shared__ float pb[TT * VCHUNK];             // 16 KB probs for this chunk
    const int tid   = threadIdx.x;
    const int b     = blockIdx.y;
    const int chunk = blockIdx.x;
    const int s0    = chunk * VCHUNK;
    const int cnt   = (SEQ - s0 < VCHUNK) ? (SEQ - s0) : VCHUNK;

#pragma unroll
    for (int t = 0; t < TT; ++t)
        for (int i = tid; i < cnt; i += 256)
            pb[t * VCHUNK + i] = scores[(size_t)(b * TT + t) * SEQ + s0 + i];
    __syncthreads();

    const int c4 = tid * 4;
    float4 acc[TT];
#pragma unroll
    for (int t = 0; t < TT; ++t) acc[t] = make_float4(0.f, 0.f, 0.f, 0.f);

    const bool tail = (s0 >= SPAST);              // block-uniform (8192 = 16*512)
    for (int i = 0; i < cnt; ++i) {
        const int s = s0 + i;
        float4 v4;
        if (!tail) {
            v4 = *(const float4*)(cache_v + ((size_t)b * SPAST + s) * CC + c4);
            *(float4*)(v_out + ((size_t)b * SEQ + s) * CC + c4) = v4;
        } else {
            v4 = *(const float4*)(v_out + ((size_t)b * SEQ + s) * CC + c4);
        }
#pragma unroll
        for (int t = 0; t < TT; ++t) {
            const float pv = pb[t * VCHUNK + i];
            acc[t].x += pv * v4.x;
            acc[t].y += pv * v4.y;
            acc[t].z += pv * v4.z;
            acc[t].w += pv * v4.w;
        }
    }
#pragma unroll
    for (int t = 0; t < TT; ++t)
        *(float4*)(ctx_part + ((size_t)chunk * BB * TT + b * TT + t) * CC + c4) = acc[t];
}

// ---------------- K5: reduce ctx partials ----------------
__global__ __launch_bounds__(256) void k_reduce_ctx(const float* __restrict__ ctx_part,
                                                    float* __restrict__ ctx) {
    const int i = blockIdx.x * 256 + threadIdx.x;   // over B*T*C/4 float4s
    float4 s = make_float4(0.f, 0.f, 0.f, 0.f);
    for (int ch = 0; ch < NCHUNK; ++ch) {
        const float4 p = *(const float4*)(ctx_part + (size_t)ch * BB * TT * CC + (size_t)i * 4);
        s.x += p.x; s.y += p.y; s.z += p.z; s.w += p.w;
    }
    *(float4*)(ctx + (size_t)i * 4) = s;
}

// ---------------- K6: out = ctx @ w_out + b_out ----------------
__global__ __launch_bounds__(256) void k_outproj(const float* __restrict__ ctx,
                                                 const float* __restrict__ w,
                                                 const float* __restrict__ bias,
                                                 float* __restrict__ out) {
    __shared__ float xs[TT * CC];
    const int tid = threadIdx.x;
    const int b   = blockIdx.y;
    const int col = blockIdx.x * 256 + tid;       // 0..1023

    const float4* src = (const float4*)(ctx + (size_t)b * TT * CC);
    float4* dst = (float4*)xs;
    for (int i = tid; i < TT * CC / 4; i += 256) dst[i] = src[i];
    __syncthreads();

    float acc[TT];
    const float bv = bias[col];
#pragma unroll
    for (int r = 0; r < TT; ++r) acc[r] = bv;
#pragma unroll 4
    for (int c = 0; c < CC; ++c) {
        const float wv = w[(size_t)c * CC + col];
#pragma unroll
        for (int r = 0; r < TT; ++r) acc[r] += xs[r * CC + c] * wv;
    }
#pragma unroll
    for (int r = 0; r < TT; ++r)
        out[(size_t)(b * TT + r) * CC + col] = acc[r];
}

extern "C" void kernel_launch(void* const* d_in, const int* in_sizes, int n_in,
                              void* d_out, int out_size, void* d_ws, size_t ws_size,
                              hipStream_t stream) {
    const float* x       = (const float*)d_in[0];
    const float* cache_k = (const float*)d_in[1];
    const float* cache_v = (const float*)d_in[2];
    const float* w_qkv   = (const float*)d_in[3];
    const float* b_qkv   = (const float*)d_in[4];
    const float* w_out   = (const float*)d_in[5];
    const float* b_out   = (const float*)d_in[6];

    float* out   = (float*)d_out;                       // [B,T,C]
    float* k_out = out + (size_t)BB * TT * CC;          // [B,SEQ,C]
    float* v_out = k_out + (size_t)BB * SEQ * CC;       // [B,SEQ,C]

    float* ws       = (float*)d_ws;
    float* q        = ws;                                // B*T*C  (scaled)
    float* scores   = q + (size_t)BB * TT * CC;          // B*T*SEQ
    float* ctx_part = scores + (size_t)BB * TT * SEQ;    // NCHUNK*B*T*C
    float* ctx      = ctx_part + (size_t)NCHUNK * BB * TT * CC;

    hipLaunchKernelGGL(k_qkv, dim3(12, 16), dim3(256), 0, stream,
                       x, w_qkv, b_qkv, q, k_out, v_out);
    hipLaunchKernelGGL(k_copyk_scores, dim3(129, 16), dim3(256), 0, stream,
                       cache_k, q, k_out, scores);
    hipLaunchKernelGGL(k_softmax, dim3(128), dim3(256), 0, stream, scores);
    hipLaunchKernelGGL(k_copyv_ctx, dim3(NCHUNK, 16), dim3(256), 0, stream,
                       cache_v, scores, v_out, ctx_part);
    hipLaunchKernelGGL(k_reduce_ctx, dim3(128), dim3(256), 0, stream, ctx_part, ctx);
    hipLaunchKernelGGL(k_outproj, dim3(4, 16), dim3(256), 0, stream,
                       ctx, w_out, b_out, out);
}